// Round 3
// baseline (52.655 us; speedup 1.0000x reference)
//
#include <hip/hip_runtime.h>

constexpr int NRES = 8192;
constexpr int NIN  = 64;
constexpr int NOUT = 32;
constexpr float DT_OVER_TAU = 0.1f / 10.0f;  // 0.01

constexpr int WAVES_PER_BLOCK = 4;           // 256 threads
constexpr int ROWS_PER_WAVE   = 4;
constexpr int NBLOCKS = NRES / (WAVES_PER_BLOCK * ROWS_PER_WAVE);  // 512

typedef float float4v __attribute__((ext_vector_type(4)));

// Fully fused reservoir step. One wave per reservoir row (4 rows/wave,
// grid-strided): no __syncthreads in the hot loop. r_new never touches
// memory; readout contribution accumulated in-register, combined per-block
// in LDS, finished with 32 atomicAdds per block onto the zeroed d_out.
__global__ __launch_bounds__(256) void reservoir_fused_kernel(
    const float* __restrict__ W,
    const float* __restrict__ W_in,
    const float* __restrict__ W_fb,
    const float* __restrict__ W_out,
    const float* __restrict__ u,
    const float* __restrict__ r,
    const float* __restrict__ yprev,
    float* __restrict__ out)
{
    const int t     = threadIdx.x;
    const int wave  = t >> 6;
    const int lane  = t & 63;
    const int gwave = blockIdx.x * WAVES_PER_BLOCK + wave;

    float yacc = 0.0f;                        // lanes 0..31: out[lane] partial

    for (int i = 0; i < ROWS_PER_WAVE; ++i) {
        const int row = gwave * ROWS_PER_WAVE + i;
        const float* wrow = W + (size_t)row * NRES;

        float acc = 0.0f;
#pragma unroll 8
        for (int j = 0; j < NRES / (64 * 4); ++j) {     // 32 iters of float4
            const int c = (j * 64 + lane) * 4;          // 1 KB/wave/iter, coalesced
            float4v wv = *reinterpret_cast<const float4v*>(wrow + c);
            float4v rv = *reinterpret_cast<const float4v*>(r + c);
            acc += wv[0] * rv[0] + wv[1] * rv[1] + wv[2] * rv[2] + wv[3] * rv[3];
        }
        // input/feedback dots folded into the same wave reduction
        acc += W_in[row * NIN + lane] * u[lane];                    // NIN == 64
        if (lane < NOUT) acc += W_fb[row * NOUT + lane] * yprev[lane];

        // butterfly: every lane ends with the full row sum
#pragma unroll
        for (int m = 32; m > 0; m >>= 1)
            acc += __shfl_xor(acc, m, 64);

        const float ri   = r[row];
        const float rnew = ri + DT_OVER_TAU * (tanhf(acc) - ri);

        if (lane < NOUT)                       // W_out column: L2-resident
            yacc += W_out[(size_t)lane * NRES + row] * rnew;
    }

    __shared__ float ybuf[WAVES_PER_BLOCK][NOUT];
    if (lane < NOUT) ybuf[wave][lane] = yacc;
    __syncthreads();

    if (wave == 0 && lane < NOUT) {
        float s = ybuf[0][lane] + ybuf[1][lane] + ybuf[2][lane] + ybuf[3][lane];
        atomicAdd(&out[lane], s);              // 512 adds/address total
    }
}

extern "C" void kernel_launch(void* const* d_in, const int* in_sizes, int n_in,
                              void* d_out, int out_size, void* d_ws, size_t ws_size,
                              hipStream_t stream) {
    // setup_inputs order: input_signal, W, W_in, W_fb, W_out, r, out_prev
    const float* u     = (const float*)d_in[0];
    const float* W     = (const float*)d_in[1];
    const float* W_in  = (const float*)d_in[2];
    const float* W_fb  = (const float*)d_in[3];
    const float* W_out = (const float*)d_in[4];
    const float* r     = (const float*)d_in[5];
    const float* yprev = (const float*)d_in[6];

    float* out = (float*)d_out;

    hipMemsetAsync(out, 0, NOUT * sizeof(float), stream);  // stream-ordered, capturable
    reservoir_fused_kernel<<<NBLOCKS, 256, 0, stream>>>(
        W, W_in, W_fb, W_out, u, r, yprev, out);
}